// Round 10
// baseline (2083.589 us; speedup 1.0000x reference)
//
#include <hip/hip_runtime.h>
#include <math.h>

#define SEQ   2048
#define BATCH 128
#define HID   256
#define VST   20   // v chunk stride in floats (80B = 5x16B, float4-aligned):
                   // 16 chunk bases -> bank quads {0,20,8,28,16,4,24,12}x2
                   // -> 2-way max on b128 reads (free)

typedef float f2 __attribute__((ext_vector_type(2)));

// Cross-lane helpers (validated rounds 6/8).
// 0xB1 = quad_perm xor1; 0x4E = quad_perm xor2; 0x128 = row_ror:8 == xor8
// within 16-lane DPP rows. ds_swizzle BitMode: 0x101F = xor4, 0x401F = xor16.
template <int CTRL>
__device__ __forceinline__ float dpp_mov(float x) {
    return __int_as_float(__builtin_amdgcn_update_dpp(
        __float_as_int(x), __float_as_int(x), CTRL, 0xF, 0xF, false));
}
template <int PAT>
__device__ __forceinline__ float swz(float x) {
    return __int_as_float(__builtin_amdgcn_ds_swizzle(__float_as_int(x), PAT));
}

// Register-residency resolution of rounds 2/4/6/8/9: the RA grants at most
// ~128-144 arch VGPRs and VALU cannot source AGPRs (round 9: v_fmac with "a"
// operand rejected by the assembler). So shrink per-thread weight state to
// fit: T=1024 (16 waves, 4 waves/EU -> 128-reg budget), 4 rows x 16 k = 64
// weight floats/thread as 32 float2 pairs, consumed by v_pk_fma_f32
// (__builtin_elementwise_fma on 2-wide vectors; 2 MACs/instr).
// Thread (R=tid>>4, l=tid&15): k-chunk [16l,16l+16), rows 4R+((tid&3)^j)
// XOR-ordered. Reduce: k-folds xor8 (DPP) + xor4 (swizzle), then xor2/xor1
// transpose -> thread ends with the full dot of row 4R+(tid&3), duplicated
// bit-identically in the 4 lanes sharing tid&3 (commutative fold order).
// Fused head (round-8 validated math, round-9 parallel finish): 5-round
// butterfly -> 32 group partials (double-buffered); wave 0 finishes y[t-1]
// with a parallel read + 5-round butterfly (no serial thread-0 chain).
__global__ __launch_bounds__(1024) __attribute__((amdgpu_waves_per_eu(4, 4)))
void rnn_scan_kernel(const float* __restrict__ x,        // (SEQ, BATCH)
                     const float* __restrict__ h0,       // (BATCH, HID)
                     const float* __restrict__ W_ih,     // (HID, 1)
                     const float* __restrict__ W_hh,     // (HID, HID)
                     const float* __restrict__ W_hh_b,   // (HID, HID)
                     const float* __restrict__ b_h,      // (HID,)
                     const float* __restrict__ W,        // (OUT, HID)
                     const float* __restrict__ bias,     // (OUT,)
                     const int*   __restrict__ context,  // scalar
                     float*       __restrict__ y,        // (BATCH, SEQ)
                     float*       __restrict__ out_hs)   // (BATCH, SEQ, HID)
{
    const int b   = blockIdx.x;
    const int tid = threadIdx.x;
    const int R   = tid >> 4;    // [0,64): row-group base 4R
    const int l   = tid & 15;    // k-chunk index
    const int l3  = tid & 3;
    const int row = 4 * R + l3;  // row this thread owns after the reduce
    const bool owner = (tid & 12) == 0;   // unique owner among the 4 dups

    __shared__ __align__(16) float v_lds[2][16 * VST];
    __shared__ float ypart[2][32];
    __shared__ float x_lds[SEQ];

    for (int t = tid; t < SEQ; t += 1024)
        x_lds[t] = x[t * BATCH + b];

    const float ctx = (float)context[0];

    // wv[j] = W_eff[4R + (l3^j)][16l .. 16l+16) as 8 float2 pairs.
    f2 wv[4][8];
    #pragma unroll
    for (int j = 0; j < 4; ++j) {
        const int rj = 4 * R + (l3 ^ j);
        const float* wp = W_hh   + (size_t)rj * HID + 16 * l;
        const float* bp = W_hh_b + (size_t)rj * HID + 16 * l;
        #pragma unroll
        for (int c4 = 0; c4 < 4; ++c4) {
            const float4 a = *(const float4*)(wp + 4 * c4);
            const float4 d = *(const float4*)(bp + 4 * c4);
            wv[j][2 * c4 + 0] = f2{a.x + ctx * d.x, a.y + ctx * d.y};
            wv[j][2 * c4 + 1] = f2{a.z + ctx * d.z, a.w + ctx * d.w};
        }
    }

    const float winj = W_ih[row];
    const float bhj  = b_h[row];
    const float w0r  = W[row];       // head weight for this row
    const float b0   = bias[0];

    const int voff = VST * (row >> 4) + (row & 15);
    if (owner)
        v_lds[0][voff] = 2.f * h0[(size_t)b * HID + row] - 1.f;

    float* outp = out_hs + (size_t)b * SEQ * HID + row;
    float* yp   = y + (size_t)b * SEQ;

    const float4* vr0 = (const float4*)(v_lds[0] + VST * l);  // 80B-stride
    const float4* vr1 = (const float4*)(v_lds[1] + VST * l);

    __syncthreads();  // v[0] + x_lds ready

    auto step = [&](int t, const float4* __restrict__ vr,
                    float* __restrict__ vw,
                    const float* __restrict__ ypr,     // ypart of step t-1
                    float* __restrict__ ypw) {         // ypart of step t
        // Early parallel read of step t-1's head partials (wave 0 only);
        // LDS latency hides under the FMA block.
        float yv = 0.f;
        if (tid < 64) yv = ypr[tid & 31];

        f2 q2[4] = {f2{0.f, 0.f}, f2{0.f, 0.f}, f2{0.f, 0.f}, f2{0.f, 0.f}};
        #pragma unroll
        for (int c4 = 0; c4 < 4; ++c4) {
            const float4 v4 = vr[c4];
            const f2 p0 = {v4.x, v4.y};
            const f2 p1 = {v4.z, v4.w};
            #pragma unroll
            for (int j = 0; j < 4; ++j) {
                q2[j] = __builtin_elementwise_fma(wv[j][2 * c4 + 0], p0, q2[j]);
                q2[j] = __builtin_elementwise_fma(wv[j][2 * c4 + 1], p1, q2[j]);
            }
        }
        float q[4];
        #pragma unroll
        for (int j = 0; j < 4; ++j) q[j] = q2[j].x + q2[j].y;

        // k-folds: lanes l<->l^8 then l<->l^4 (same tid&3 -> same rows,
        // complementary chunks). Then XOR transpose over lane bits 1,0.
        #pragma unroll
        for (int j = 0; j < 4; ++j) q[j] += dpp_mov<0x128>(q[j]);  // xor8
        #pragma unroll
        for (int j = 0; j < 4; ++j) q[j] += swz<0x101F>(q[j]);     // xor4
        q[0] += dpp_mov<0x4E>(q[2]);    // xor2: lane l^2's q[2] is my row
        q[1] += dpp_mov<0x4E>(q[3]);
        q[0] += dpp_mov<0xB1>(q[1]);    // xor1
        // q[0] = full dot for row 4R+l3 (bit-identical in the 4 dup lanes)

        const float pre = q[0] + bhj + x_lds[t] * winj;
        const float h = 1.f / (1.f + __expf(-pre));

        // Fused head, stage 1: owners contribute h*W0[row]; 5-round butterfly
        // -> each 32-lane group's sum; one writer per group.
        float yc = owner ? h * w0r : 0.f;
        yc += dpp_mov<0xB1>(yc);
        yc += dpp_mov<0x4E>(yc);
        yc += swz<0x101F>(yc);
        yc += dpp_mov<0x128>(yc);
        yc += swz<0x401F>(yc);
        if ((tid & 31) == 0) ypw[tid >> 5] = yc;

        // Fused head, stage 2 (wave 0, parallel): finish y[t-1] by summing
        // the 32 partials read before the FMA block.
        if (tid < 64) {
            yv += dpp_mov<0xB1>(yv);
            yv += dpp_mov<0x4E>(yv);
            yv += swz<0x101F>(yv);
            yv += dpp_mov<0x128>(yv);
            yv += swz<0x401F>(yv);
            if (tid == 0 && t > 0) yp[t - 1] = yv + b0;
        }

        if (owner) {
            vw[voff] = 2.f * h - 1.f;       // 16 lanes/wave, 16 distinct banks
            outp[(size_t)t * HID] = h;      // 16 lanes over a 64B window
        }
        __syncthreads();  // v[t+1] + ypart[t] ready; buffers fully read
    };

    for (int t = 0; t < SEQ; t += 2) {
        step(t,     vr0, v_lds[1], ypart[1], ypart[0]);
        step(t + 1, vr1, v_lds[0], ypart[0], ypart[1]);
    }

    // Final step's y (SEQ-1 odd -> partials in ypart[1]).
    if (tid < 64) {
        float yv = ypart[(SEQ - 1) & 1][tid & 31];
        yv += dpp_mov<0xB1>(yv);
        yv += dpp_mov<0x4E>(yv);
        yv += swz<0x101F>(yv);
        yv += dpp_mov<0x128>(yv);
        yv += swz<0x401F>(yv);
        if (tid == 0) yp[SEQ - 1] = yv + b0;
    }
}

extern "C" void kernel_launch(void* const* d_in, const int* in_sizes, int n_in,
                              void* d_out, int out_size, void* d_ws, size_t ws_size,
                              hipStream_t stream) {
    const float* x      = (const float*)d_in[0];
    const float* h0     = (const float*)d_in[1];
    const float* W_ih   = (const float*)d_in[2];
    const float* W_hh   = (const float*)d_in[3];
    const float* W_hh_b = (const float*)d_in[4];
    const float* b_h    = (const float*)d_in[5];
    const float* W      = (const float*)d_in[6];
    const float* bias   = (const float*)d_in[7];
    const int*   ctx    = (const int*)d_in[8];

    float* y  = (float*)d_out;                // (BATCH*SEQ,) = y[:,:,0]
    float* hs = y + (size_t)BATCH * SEQ;      // (BATCH, SEQ, HID) = out

    rnn_scan_kernel<<<BATCH, 1024, 0, stream>>>(x, h0, W_ih, W_hh, W_hh_b,
                                                b_h, W, bias, ctx, y, hs);
}

// Round 11
// 1696.039 us; speedup vs baseline: 1.2285x; 1.2285x over previous
//
#include <hip/hip_runtime.h>
#include <math.h>

#define SEQ   2048
#define BATCH 128
#define HID   256
#define VST   20   // v chunk stride in floats (80B): 16 chunk bases -> 8 bank
                   // quads x 2 addrs = 2-way max on b128 reads (free)

// Cross-lane helpers (validated rounds 6/8).
// 0xB1 = quad_perm xor1; 0x4E = quad_perm xor2; 0x128 = row_ror:8 == xor8
// within 16-lane DPP rows. ds_swizzle BitMode: 0x101F = xor4, 0x401F = xor16.
template <int CTRL>
__device__ __forceinline__ float dpp_mov(float x) {
    return __int_as_float(__builtin_amdgcn_update_dpp(
        __float_as_int(x), __float_as_int(x), CTRL, 0xF, 0xF, false));
}
template <int PAT>
__device__ __forceinline__ float swz(float x) {
    return __int_as_float(__builtin_amdgcn_ds_swizzle(__float_as_int(x), PAT));
}

// Register-residency hypothesis (rounds 2/4/6/8/10): the RA always grants
// ~budget/2 arch VGPRs and AGPR-spills the weights. The t-loop needs only
// ~180 regs (fits 256); the spill trigger is the PREAMBLE - the unrolled
// weight-init hoists up to 128 float4 loads in flight (512 regs transient).
// Fix under test: sched_barrier(0) after each row's init caps the preamble
// at <=8 loads in flight, so the RA never sees inflated pressure and the
// weights stay arch-resident through the whole kernel.
__global__ __launch_bounds__(512) __attribute__((amdgpu_waves_per_eu(2, 2)))
void rnn_scan_kernel(const float* __restrict__ x,        // (SEQ, BATCH)
                     const float* __restrict__ h0,       // (BATCH, HID)
                     const float* __restrict__ W_ih,     // (HID, 1)
                     const float* __restrict__ W_hh,     // (HID, HID)
                     const float* __restrict__ W_hh_b,   // (HID, HID)
                     const float* __restrict__ b_h,      // (HID,)
                     const float* __restrict__ W,        // (OUT, HID)
                     const float* __restrict__ bias,     // (OUT,)
                     const int*   __restrict__ context,  // scalar
                     float*       __restrict__ y,        // (BATCH, SEQ)
                     float*       __restrict__ out_hs)   // (BATCH, SEQ, HID)
{
    const int b   = blockIdx.x;
    const int tid = threadIdx.x;
    const int R   = tid >> 4;    // row-group: rows [8R, 8R+8)
    const int l   = tid & 15;    // k-chunk index
    const int l7  = tid & 7;
    const int row = 8 * R + l7;  // row this thread owns after the reduce

    __shared__ __align__(16) float v_lds[2][16 * VST];
    __shared__ float ypart[2][16];
    __shared__ float x_lds[SEQ];

    for (int t = tid; t < SEQ; t += 512)
        x_lds[t] = x[t * BATCH + b];

    const float ctx = (float)context[0];

    // wreg[j][c] = W_eff[8R + (l7^j)][16l + 4c .. +3]  (XOR-ordered rows).
    // sched_barrier(0) per row: preamble pressure stays ~32 regs.
    float4 wreg[8][4];
    #pragma unroll
    for (int j = 0; j < 8; ++j) {
        const int rj = 8 * R + (l7 ^ j);
        const float* wp = W_hh   + (size_t)rj * HID + 16 * l;
        const float* bp = W_hh_b + (size_t)rj * HID + 16 * l;
        #pragma unroll
        for (int c = 0; c < 4; ++c) {
            const float4 a = *(const float4*)(wp + 4 * c);
            const float4 d = *(const float4*)(bp + 4 * c);
            wreg[j][c] = make_float4(a.x + ctx * d.x, a.y + ctx * d.y,
                                     a.z + ctx * d.z, a.w + ctx * d.w);
        }
        __builtin_amdgcn_sched_barrier(0);
    }

    const float winj = W_ih[row];
    const float bhj  = b_h[row];
    const float w0r  = W[row];       // head weight for this row
    const float b0   = bias[0];

    const int voff = VST * (row >> 4) + (row & 15);
    v_lds[0][voff] = 2.f * h0[(size_t)b * HID + row] - 1.f;  // dup-safe

    float* outp = out_hs + (size_t)b * SEQ * HID + row;
    float* yp   = y + (size_t)b * SEQ;

    const float4* vr0 = (const float4*)(v_lds[0] + VST * l);  // 80B-stride
    const float4* vr1 = (const float4*)(v_lds[1] + VST * l);

    __syncthreads();  // v[0] + x_lds ready

    auto step = [&](int t, const float4* __restrict__ vr,
                    float* __restrict__ vw,
                    const float* __restrict__ ypr,     // ypart of step t-1
                    float* __restrict__ ypw) {         // ypart of step t
        // Early parallel read of step t-1's head partials (wave 0 only);
        // LDS latency hides under the FMA block.
        float yv = 0.f;
        if (tid < 64) yv = ypr[tid & 15];

        float q[8] = {0.f, 0.f, 0.f, 0.f, 0.f, 0.f, 0.f, 0.f};
        #pragma unroll
        for (int c = 0; c < 4; ++c) {
            const float4 v4 = vr[c];
            #pragma unroll
            for (int j = 0; j < 8; ++j) {
                const float4 w = wreg[j][c];
                q[j] += w.x * v4.x;
                q[j] += w.y * v4.y;
                q[j] += w.z * v4.z;
                q[j] += w.w * v4.w;
            }
        }
        // Fold l <-> l^8 (same rows, complementary k-halves), then XOR
        // transpose small-mask-first; only xor4 touches the LDS pipe.
        #pragma unroll
        for (int j = 0; j < 8; ++j) q[j] += dpp_mov<0x128>(q[j]);
        q[0] += dpp_mov<0xB1>(q[1]);
        q[2] += dpp_mov<0xB1>(q[3]);
        q[4] += dpp_mov<0xB1>(q[5]);
        q[6] += dpp_mov<0xB1>(q[7]);
        q[0] += dpp_mov<0x4E>(q[2]);
        q[4] += dpp_mov<0x4E>(q[6]);
        q[0] += swz<0x101F>(q[4]);
        // q[0] = full dot for row 8R+l7 (bit-identical dup in tid^8)

        const float pre = q[0] + bhj + x_lds[t] * winj;
        const float h = 1.f / (1.f + __expf(-pre));

        // Fused head, stage 1 (validated round 8): 32-lane butterfly -> 16
        // group partials, one writer per 32-lane group.
        float yc = ((tid & 8) == 0) ? h * w0r : 0.f;
        yc += dpp_mov<0xB1>(yc);
        yc += dpp_mov<0x4E>(yc);
        yc += swz<0x101F>(yc);
        yc += dpp_mov<0x128>(yc);
        yc += swz<0x401F>(yc);
        if ((tid & 31) == 0) ypw[tid >> 5] = yc;

        // Fused head, stage 2 (wave 0, PARALLEL - round 8's serial tid==0
        // sum cost ~200 cyc/step): butterfly over the 16 slots read early.
        if (tid < 64) {
            yv += dpp_mov<0xB1>(yv);
            yv += dpp_mov<0x4E>(yv);
            yv += swz<0x101F>(yv);
            yv += dpp_mov<0x128>(yv);
            if (tid == 0 && t > 0) yp[t - 1] = yv + b0;
        }

        vw[voff] = 2.f * h - 1.f;       // dup write, same value: benign
        if ((tid & 8) == 0)
            outp[(size_t)t * HID] = h;  // coalesced store, rows 32w..+32

        __syncthreads();  // v[t+1] + ypart[t] ready; buffers fully read
    };

    for (int t = 0; t < SEQ; t += 2) {
        step(t,     vr0, v_lds[1], ypart[1], ypart[0]);
        step(t + 1, vr1, v_lds[0], ypart[0], ypart[1]);
    }

    // Final step's y (SEQ-1 odd -> partials in ypart[1]).
    if (tid < 64) {
        float yv = ypart[(SEQ - 1) & 1][tid & 15];
        yv += dpp_mov<0xB1>(yv);
        yv += dpp_mov<0x4E>(yv);
        yv += swz<0x101F>(yv);
        yv += dpp_mov<0x128>(yv);
        if (tid == 0) yp[SEQ - 1] = yv + b0;
    }
}

extern "C" void kernel_launch(void* const* d_in, const int* in_sizes, int n_in,
                              void* d_out, int out_size, void* d_ws, size_t ws_size,
                              hipStream_t stream) {
    const float* x      = (const float*)d_in[0];
    const float* h0     = (const float*)d_in[1];
    const float* W_ih   = (const float*)d_in[2];
    const float* W_hh   = (const float*)d_in[3];
    const float* W_hh_b = (const float*)d_in[4];
    const float* b_h    = (const float*)d_in[5];
    const float* W      = (const float*)d_in[6];
    const float* bias   = (const float*)d_in[7];
    const int*   ctx    = (const int*)d_in[8];

    float* y  = (float*)d_out;                // (BATCH*SEQ,) = y[:,:,0]
    float* hs = y + (size_t)BATCH * SEQ;      // (BATCH, SEQ, HID) = out

    rnn_scan_kernel<<<BATCH, 512, 0, stream>>>(x, h0, W_ih, W_hh, W_hh_b,
                                               b_h, W, bias, ctx, y, hs);
}